// Round 1
// 368.125 us; speedup vs baseline: 1.0101x; 1.0101x over previous
//
#include <hip/hip_runtime.h>
#include <math.h>

// Problem constants (fixed by the reference setup_inputs)
constexpr int DIM    = 512;
constexpr int NTOK   = 16384;
constexpr int NBATCH = 8;
constexpr int CHUNK  = 32;               // tokens per wave-chunk (was 64: halved for 2x occupancy)
constexpr int CPB    = NTOK / CHUNK;     // 512 chunks per batch
constexpr int WPB    = 4;                // waves per block (256 threads)
constexpr int NCHUNKS = NBATCH * CPB;    // 4096 total chunks
constexpr int S2_CHUNKS = 32;            // chunks reduced per stage2 block
constexpr int S2_BLOCKS_PER_B = CPB / S2_CHUNKS;    // 16
constexpr int S2_BLOCKS = NBATCH * S2_BLOCKS_PER_B; // 128

// Scores s = tanh(za)*sigmoid(zg) are bounded in (-1,1): softmax needs no
// max subtraction (exp(s) can't overflow; sum over 16384 tokens ~4e4).

// Stage 1: one wave = one 32-token chunk. Lane i owns row elements [4i,4i+4)
// and [256+4i,256+4i+4) -> two coalesced 1KiB float4 wave loads per token.
//
// Token-PAIR packed reduction: fold (da0,dg0,da1,dg1) into lane classes mod 4
// with 6 shuffles, butterfly offsets 4..32 (4 shuffles), then 2 swap shuffles.
// => 12 shuffles per 2 tokens (was 8/token) AND the tanh/sigmoid/exp chain
// executes once per 2 tokens (lane groups specialize), halving transcendental
// work and shortening the serial chain that was starving HBM.
__global__ __launch_bounds__(256, 4)
void ga_stage1(const float* __restrict__ x,
               const float* __restrict__ Wa, const float* __restrict__ ba,
               const float* __restrict__ Wg, const float* __restrict__ bg,
               float* __restrict__ wl, float* __restrict__ wv)
{
    const int lane = threadIdx.x & 63;
    const int wave = threadIdx.x >> 6;
    const int gw   = blockIdx.x * WPB + wave;   // global chunk id, 0..4095
    const int b    = gw / CPB;
    const int c    = gw % CPB;
    const bool even = (lane & 1) == 0;

    const float4* xq = (const float4*)(x + ((size_t)b * NTOK + (size_t)c * CHUNK) * DIM);

    const float4 wa0 = ((const float4*)Wa)[lane];
    const float4 wa1 = ((const float4*)Wa)[64 + lane];
    const float4 wg0 = ((const float4*)Wg)[lane];
    const float4 wg1 = ((const float4*)Wg)[64 + lane];
    const float bav = ba[0], bgv = bg[0];

    float l = 0.0f;
    float a0x=0.f,a0y=0.f,a0z=0.f,a0w=0.f;
    float a1x=0.f,a1y=0.f,a1z=0.f,a1w=0.f;

    constexpr int U = 4;               // tokens per group (prefetch depth)
    constexpr int G = CHUNK / U;       // 8 groups

    float4 b0[U], b1[U];
    #pragma unroll
    for (int u = 0; u < U; ++u) {
        b0[u] = xq[u * 128 + lane];        // token u, first 256 floats
        b1[u] = xq[u * 128 + 64 + lane];   // token u, second 256 floats
    }

    for (int g = 0; g < G; ++g) {
        float4 n0[U], n1[U];
        if (g + 1 < G) {
            const float4* nq = xq + (size_t)(g + 1) * U * 128;
            #pragma unroll
            for (int u = 0; u < U; ++u) {
                n0[u] = nq[u * 128 + lane];
                n1[u] = nq[u * 128 + 64 + lane];
            }
        }
        #pragma unroll
        for (int u = 0; u < U; u += 2) {
            // partial dots for the token pair (u, u+1)
            float da0 = b0[u].x*wa0.x + b0[u].y*wa0.y + b0[u].z*wa0.z + b0[u].w*wa0.w
                      + b1[u].x*wa1.x + b1[u].y*wa1.y + b1[u].z*wa1.z + b1[u].w*wa1.w;
            float dg0 = b0[u].x*wg0.x + b0[u].y*wg0.y + b0[u].z*wg0.z + b0[u].w*wg0.w
                      + b1[u].x*wg1.x + b1[u].y*wg1.y + b1[u].z*wg1.z + b1[u].w*wg1.w;
            float da1 = b0[u+1].x*wa0.x + b0[u+1].y*wa0.y + b0[u+1].z*wa0.z + b0[u+1].w*wa0.w
                      + b1[u+1].x*wa1.x + b1[u+1].y*wa1.y + b1[u+1].z*wa1.z + b1[u+1].w*wa1.w;
            float dg1 = b0[u+1].x*wg0.x + b0[u+1].y*wg0.y + b0[u+1].z*wg0.z + b0[u+1].w*wg0.w
                      + b1[u+1].x*wg1.x + b1[u+1].y*wg1.y + b1[u+1].z*wg1.z + b1[u+1].w*wg1.w;

            // fold offset 1: even lanes carry da trees, odd lanes dg trees
            const float t0 = da0 + __shfl_xor(da0, 1, 64);
            const float t1 = dg0 + __shfl_xor(dg0, 1, 64);
            const float w0 = even ? t0 : t1;
            const float t2 = da1 + __shfl_xor(da1, 1, 64);
            const float t3 = dg1 + __shfl_xor(dg1, 1, 64);
            const float w1 = even ? t2 : t3;
            // fold offset 2: lane&3 == {0:da0, 1:dg0, 2:da1, 3:dg1}
            const float u0 = w0 + __shfl_xor(w0, 2, 64);
            const float u1 = w1 + __shfl_xor(w1, 2, 64);
            float v = (lane & 2) ? u1 : u0;
            // butterfly over remaining offsets (preserve lane&3 classes)
            #pragma unroll
            for (int off = 4; off <= 32; off <<= 1)
                v += __shfl_xor(v, off, 64);
            // v = S_{lane&3}; partner swap gives (da,dg) for this lane's token
            const float vp  = __shfl_xor(v, 1, 64);
            const float daf = even ? v : vp;
            const float dgf = even ? vp : v;
            // each lane computes the transcendental chain for token t=(lane>>1)&1
            const float s = tanhf(daf + bav) / (1.0f + expf(-(dgf + bgv)));
            const float p = expf(s);
            const float q = __shfl_xor(p, 2, 64);       // other token's p
            const float p0 = (lane & 2) ? q : p;
            const float p1 = (lane & 2) ? p : q;

            l += p0 + p1;
            a0x += p0*b0[u].x + p1*b0[u+1].x;  a0y += p0*b0[u].y + p1*b0[u+1].y;
            a0z += p0*b0[u].z + p1*b0[u+1].z;  a0w += p0*b0[u].w + p1*b0[u+1].w;
            a1x += p0*b1[u].x + p1*b1[u+1].x;  a1y += p0*b1[u].y + p1*b1[u+1].y;
            a1z += p0*b1[u].z + p1*b1[u+1].z;  a1w += p0*b1[u].w + p1*b1[u+1].w;
        }
        if (g + 1 < G) {
            #pragma unroll
            for (int u = 0; u < U; ++u) { b0[u] = n0[u]; b1[u] = n1[u]; }
        }
    }

    if (lane == 0) wl[gw] = l;
    float4* vq = (float4*)(wv + (size_t)gw * DIM);
    vq[lane]      = make_float4(a0x, a0y, a0z, a0w);
    vq[64 + lane] = make_float4(a1x, a1y, a1z, a1w);
}

// Stage 2: tree level 1 — each block reduces 32 chunk-partials.
__global__ __launch_bounds__(256)
void ga_stage2(const float* __restrict__ wl, const float* __restrict__ wv,
               float* __restrict__ l2, float* __restrict__ v2)
{
    const int bb  = blockIdx.x;            // 0..127: (batch, j)
    const int tid = threadIdx.x;
    const int cid0 = bb * S2_CHUNKS;       // chunks are batch-contiguous

    float acc0 = 0.0f, acc1 = 0.0f;
    const float* vb = wv + (size_t)cid0 * DIM;
    #pragma unroll 4
    for (int c = 0; c < S2_CHUNKS; ++c) {
        acc0 += vb[(size_t)c * DIM + tid];
        acc1 += vb[(size_t)c * DIM + 256 + tid];
    }
    v2[(size_t)bb * DIM + tid]       = acc0;
    v2[(size_t)bb * DIM + 256 + tid] = acc1;

    if (tid < 64) {
        float lv = (tid < S2_CHUNKS) ? wl[cid0 + tid] : 0.0f;
        #pragma unroll
        for (int off = 32; off > 0; off >>= 1) lv += __shfl_xor(lv, off, 64);
        if (tid == 0) l2[bb] = lv;
    }
}

// Stage 3: tree level 2 — combine 16 partials per batch, divide by L.
__global__ __launch_bounds__(256)
void ga_stage3(const float* __restrict__ l2, const float* __restrict__ v2,
               float* __restrict__ out)
{
    const int b   = blockIdx.x;
    const int tid = threadIdx.x;

    float L = 0.0f;
    #pragma unroll
    for (int j = 0; j < S2_BLOCKS_PER_B; ++j) L += l2[b * S2_BLOCKS_PER_B + j];

    float a0 = 0.0f, a1 = 0.0f;
    const float* vb = v2 + (size_t)b * S2_BLOCKS_PER_B * DIM;
    #pragma unroll
    for (int j = 0; j < S2_BLOCKS_PER_B; ++j) {
        a0 += vb[(size_t)j * DIM + tid];
        a1 += vb[(size_t)j * DIM + 256 + tid];
    }
    const float invL = 1.0f / L;
    out[(size_t)b * DIM + tid]       = a0 * invL;
    out[(size_t)b * DIM + 256 + tid] = a1 * invL;
}

extern "C" void kernel_launch(void* const* d_in, const int* in_sizes, int n_in,
                              void* d_out, int out_size, void* d_ws, size_t ws_size,
                              hipStream_t stream)
{
    const float* x  = (const float*)d_in[0];
    const float* Wa = (const float*)d_in[1];
    const float* ba = (const float*)d_in[2];
    const float* Wg = (const float*)d_in[3];
    const float* bg = (const float*)d_in[4];
    float* out = (float*)d_out;

    // ws layout: wl[4096] | wv[4096*512] | l2[128] | v2[128*512]  (~8.7 MiB)
    float* wl = (float*)d_ws;
    float* wv = wl + NCHUNKS;
    float* l2 = wv + (size_t)NCHUNKS * DIM;
    float* v2 = l2 + S2_BLOCKS;

    ga_stage1<<<NCHUNKS / WPB, 256, 0, stream>>>(x, Wa, ba, Wg, bg, wl, wv);
    ga_stage2<<<S2_BLOCKS, 256, 0, stream>>>(wl, wv, l2, v2);
    ga_stage3<<<NBATCH, 256, 0, stream>>>(l2, v2, out);
}